// Round 2
// baseline (181.037 us; speedup 1.0000x reference)
//
#include <hip/hip_runtime.h>

// Problem constants (from reference): B=32, Z=4000, IN=32, H=64, E=64000
#define B_   32
#define Z_   4000
#define IN_  32
#define H_   64
#define E_   64000
#define NBZ  (B_ * Z_)          // 128000 node-batch pairs
#define NB_V (NBZ / 256)        // 500 blocks (exact)
#define NB_E ((E_ + 255) / 256) // 250 blocks (exact)

// Fused: v[b,z] = x[b,z,:] . (W @ fc_W)   and   deg[z] = #in-edges(z)
__global__ void k_v_deg(const float* __restrict__ x,      // [B,Z,IN] fp32
                        const int* __restrict__ edge,     // [2,E]: row0=src, row1=dst
                        const float* __restrict__ W,      // [IN,H]
                        const float* __restrict__ fcW,    // [H,1]
                        float* __restrict__ v,
                        int* __restrict__ deg) {
    if (blockIdx.x < NB_V) {
        __shared__ float w2s[IN_];
        const int tid = threadIdx.x;
        if (tid < IN_) {
            // redundant per-block w2 = W @ fc_W (2048 MACs, L2-cached reads)
            float s = 0.f;
            #pragma unroll 8
            for (int h = 0; h < H_; ++h)
                s += W[tid * H_ + h] * fcW[h];
            w2s[tid] = s;
        }
        __syncthreads();
        const int n = blockIdx.x * 256 + tid;               // n < 128000 exactly
        const float4* xp = (const float4*)(x + (size_t)n * IN_); // 128B row, aligned
        float s = 0.f;
        #pragma unroll
        for (int i = 0; i < IN_ / 4; ++i) {
            float4 f = xp[i];
            s += f.x * w2s[4 * i]     + f.y * w2s[4 * i + 1]
               + f.z * w2s[4 * i + 2] + f.w * w2s[4 * i + 3];
        }
        v[n] = s;
    } else {
        const int e = (blockIdx.x - NB_V) * 256 + threadIdx.x;
        if (e < E_) atomicAdd(&deg[edge[E_ + e]], 1);       // dst row
    }
}

// out[b,z] = c + dinv[z]^2 * v[b,z]   (self-loop term); also publish dinv[z]
__global__ void k_init(const float* __restrict__ v,
                       const int* __restrict__ deg,
                       const float* __restrict__ bias,     // [H]
                       const float* __restrict__ fcW,      // [H,1]
                       const float* __restrict__ fcb,      // [1]
                       float* __restrict__ out,            // [B,Z] == d_out
                       float* __restrict__ dinv) {
    __shared__ float cs;
    if (threadIdx.x == 0) {
        float c = fcb[0];
        for (int h = 0; h < H_; ++h) c += bias[h] * fcW[h];
        cs = c;
    }
    __syncthreads();
    const int n = blockIdx.x * 256 + threadIdx.x;           // n < 128000
    const int z = n % Z_;
    const float di = rsqrtf((float)(deg[z] + 1));           // +1 = self loop
    out[n] = cs + di * di * v[n];
    if (n < Z_) dinv[n] = di;                               // b==0 threads cover all z
}

// out[b,dst] += dinv[src]*dinv[dst]*v[b,src]  over all (b,e)
__global__ void k_scatter(const int* __restrict__ edge,
                          const float* __restrict__ dinv,
                          const float* __restrict__ v,
                          float* __restrict__ out) {
    const int t = blockIdx.x * 256 + threadIdx.x;           // t < B*E (exact grid)
    const int e = t % E_;                                   // consecutive lanes -> consecutive edges
    const int b = t / E_;                                   // one b per 250-block band (L1-friendly v slice)
    const int s = edge[e];
    const int d = edge[E_ + e];
    const float nrm = dinv[s] * dinv[d];
    atomicAdd(&out[b * Z_ + d], nrm * v[b * Z_ + s]);
}

extern "C" void kernel_launch(void* const* d_in, const int* in_sizes, int n_in,
                              void* d_out, int out_size, void* d_ws, size_t ws_size,
                              hipStream_t stream) {
    const float* x    = (const float*)d_in[0];   // [B,Z,IN]
    const int*   edge = (const int*)d_in[1];     // [2,E]
    const float* W    = (const float*)d_in[2];   // [IN,H]
    const float* bias = (const float*)d_in[3];   // [H]
    const float* fcW  = (const float*)d_in[4];   // [H,1]
    const float* fcb  = (const float*)d_in[5];   // [1]
    float* out = (float*)d_out;                  // [B,Z] fp32

    // workspace layout (~528 KB; ws re-poisoned 0xAA each call — all regions
    // fully rewritten every launch before being read)
    float* v    = (float*)d_ws;       // B*Z fp32
    float* dinv = v + NBZ;            // Z fp32
    int*   deg  = (int*)(dinv + Z_);  // Z int

    hipMemsetAsync(deg, 0, Z_ * sizeof(int), stream);
    k_v_deg  <<<NB_V + NB_E,     256, 0, stream>>>(x, edge, W, fcW, v, deg);
    k_init   <<<NB_V,            256, 0, stream>>>(v, deg, bias, fcW, fcb, out, dinv);
    k_scatter<<<(B_ * E_) / 256, 256, 0, stream>>>(edge, dinv, v, out);
}

// Round 3
// 111.185 us; speedup vs baseline: 1.6283x; 1.6283x over previous
//
#include <hip/hip_runtime.h>

// Problem constants (from reference): B=32, Z=4000, IN=32, H=64, E=64000
#define B_   32
#define Z_   4000
#define IN_  32
#define H_   64
#define E_   64000
#define NBZ  (B_ * Z_)          // 128000 node-batch pairs
#define NB_V (NBZ / 256)        // 500 blocks (exact)
#define NB_E ((E_ + 255) / 256) // 250 blocks (exact)

// Fused: v_t[z*32+b] = x[b,z,:] . (W @ fc_W)   and   deg[z] = in-degree histogram
__global__ void k_v_deg(const float* __restrict__ x,      // [B,Z,IN] fp32
                        const int* __restrict__ edge,     // [2,E]: row0=src, row1=dst
                        const float* __restrict__ W,      // [IN,H]
                        const float* __restrict__ fcW,    // [H,1]
                        float* __restrict__ v_t,          // [Z,B] transposed
                        int* __restrict__ deg) {
    if (blockIdx.x < NB_V) {
        __shared__ float w2s[IN_];
        const int tid = threadIdx.x;
        if (tid < IN_) {
            // redundant per-block w2 = W @ fc_W (2048 MACs, L2-cached reads)
            float s = 0.f;
            #pragma unroll 8
            for (int h = 0; h < H_; ++h)
                s += W[tid * H_ + h] * fcW[h];
            w2s[tid] = s;
        }
        __syncthreads();
        const int n = blockIdx.x * 256 + tid;               // n < 128000 exactly
        const float4* xp = (const float4*)(x + (size_t)n * IN_); // 128B row, aligned
        float s = 0.f;
        #pragma unroll
        for (int i = 0; i < IN_ / 4; ++i) {
            float4 f = xp[i];
            s += f.x * w2s[4 * i]     + f.y * w2s[4 * i + 1]
               + f.z * w2s[4 * i + 2] + f.w * w2s[4 * i + 3];
        }
        const int b = n / Z_, z = n - b * Z_;
        v_t[z * B_ + b] = s;                                // transposed store (L2-absorbed)
    } else {
        const int e = (blockIdx.x - NB_V) * 256 + threadIdx.x;
        if (e < E_) atomicAdd(&deg[edge[E_ + e]], 1);       // dst row
    }
}

// Single block: exclusive scan of deg -> rowptr/cursor, dinv = rsqrt(deg+1),
// and the scalar constant c = fc_b + bias . fc_W.
__global__ void k_scan(const int* __restrict__ deg,
                       int* __restrict__ rowptr,           // [Z+1]
                       int* __restrict__ cursor,           // [Z]
                       float* __restrict__ dinv,           // [Z]
                       const float* __restrict__ bias,     // [H]
                       const float* __restrict__ fcW,      // [H,1]
                       const float* __restrict__ fcb,      // [1]
                       float* __restrict__ cdev) {         // [1]
    __shared__ int part[256];
    const int tid = threadIdx.x;
    const int base = tid * 16;                              // 256*16 = 4096 >= Z
    int loc[16];
    int s = 0;
    #pragma unroll
    for (int j = 0; j < 16; ++j) {
        const int idx = base + j;
        const int d = (idx < Z_) ? deg[idx] : 0;
        loc[j] = s;                                         // thread-local exclusive prefix
        s += d;
        if (idx < Z_) dinv[idx] = rsqrtf((float)(d + 1));   // +1 = self loop
    }
    part[tid] = s;
    __syncthreads();
    // Hillis-Steele inclusive scan over 256 partials
    for (int off = 1; off < 256; off <<= 1) {
        const int t = (tid >= off) ? part[tid - off] : 0;
        __syncthreads();
        part[tid] += t;
        __syncthreads();
    }
    const int excl = part[tid] - s;                         // exclusive block prefix
    #pragma unroll
    for (int j = 0; j < 16; ++j) {
        const int idx = base + j;
        if (idx < Z_) {
            const int r = excl + loc[j];
            rowptr[idx] = r;
            cursor[idx] = r;
        }
    }
    if (tid == 0) {
        rowptr[Z_] = E_;                                    // all dst in [0,Z)
        float c = fcb[0];
        for (int h = 0; h < H_; ++h) c += bias[h] * fcW[h];
        cdev[0] = c;
    }
}

// Bucket-fill: sorted_src[pos] = src, grouped by dst (64K cheap atomics)
__global__ void k_bucket(const int* __restrict__ edge,
                         int* __restrict__ cursor,
                         int* __restrict__ sorted_src) {
    const int e = blockIdx.x * 256 + threadIdx.x;
    if (e < E_) {
        const int s = edge[e];
        const int d = edge[E_ + e];
        const int pos = atomicAdd(&cursor[d], 1);
        sorted_src[pos] = s;
    }
}

// Gather: out[b,z] = c + dinv[z]*(dinv[z]*v[b,z] + sum_e dinv[s]*v[b,s])
// Lane map b = t&31: src-index/dinv loads broadcast across 32 lanes sharing z;
// v_t row load is one coalesced 128B line per edge visit.
__global__ void k_gather(const int* __restrict__ rowptr,
                         const int* __restrict__ sorted_src,
                         const float* __restrict__ dinv,
                         const float* __restrict__ v_t,    // [Z,B]
                         const float* __restrict__ cdev,
                         float* __restrict__ out) {        // [B,Z]
    const int t = blockIdx.x * 256 + threadIdx.x;           // t < 128000 (exact grid)
    const int b = t & (B_ - 1);
    const int z = t >> 5;                                   // 32 lanes share z
    const float di = dinv[z];
    float acc = di * v_t[(z << 5) + b];                     // self-loop term
    const int e0 = rowptr[z], e1 = rowptr[z + 1];
    for (int e = e0; e < e1; ++e) {
        const int s = sorted_src[e];
        acc += dinv[s] * v_t[(s << 5) + b];
    }
    out[b * Z_ + z] = cdev[0] + di * acc;
}

extern "C" void kernel_launch(void* const* d_in, const int* in_sizes, int n_in,
                              void* d_out, int out_size, void* d_ws, size_t ws_size,
                              hipStream_t stream) {
    const float* x    = (const float*)d_in[0];   // [B,Z,IN]
    const int*   edge = (const int*)d_in[1];     // [2,E]
    const float* W    = (const float*)d_in[2];   // [IN,H]
    const float* bias = (const float*)d_in[3];   // [H]
    const float* fcW  = (const float*)d_in[4];   // [H,1]
    const float* fcb  = (const float*)d_in[5];   // [1]
    float* out = (float*)d_out;                  // [B,Z] fp32

    // workspace layout (~1.1 MB; ws re-poisoned 0xAA each call — every region
    // is fully rewritten before being read each launch)
    float* v_t    = (float*)d_ws;                // B*Z fp32 (transposed [Z,B])
    float* dinv   = v_t + NBZ;                   // Z fp32
    float* cdev   = dinv + Z_;                   // 1 fp32
    int*   deg    = (int*)(cdev + 1);            // Z int
    int*   rowptr = deg + Z_;                    // Z+1 int
    int*   cursor = rowptr + Z_ + 1;             // Z int
    int*   srt    = cursor + Z_;                 // E int (src sorted by dst)

    hipMemsetAsync(deg, 0, Z_ * sizeof(int), stream);
    k_v_deg <<<NB_V + NB_E, 256, 0, stream>>>(x, edge, W, fcW, v_t, deg);
    k_scan  <<<1,           256, 0, stream>>>(deg, rowptr, cursor, dinv, bias, fcW, fcb, cdev);
    k_bucket<<<NB_E,        256, 0, stream>>>(edge, cursor, srt);
    k_gather<<<NB_V,        256, 0, stream>>>(rowptr, srt, dinv, v_t, cdev, out);
}